// Round 4
// baseline (198.703 us; speedup 1.0000x reference)
//
#include <hip/hip_runtime.h>
#include <math.h>

typedef unsigned short u16;
typedef unsigned int u32;

#define NBATCH 16
#define NCH    256
#define NPIX   4096
#define NHEAD  4
#define HDIM   32
#define NMEM   4
#define HID    128
#define OC3    384
#define SCALE_Q 0.17677669529663687f

typedef __bf16 bf16x8 __attribute__((ext_vector_type(8)));
typedef float  f32x4  __attribute__((ext_vector_type(4)));

__device__ __forceinline__ float bf2f(u16 u){ return __uint_as_float(((u32)u)<<16); }
// native casts -> compiler emits v_cvt_pk_bf16_f32 (RNE, same as old manual RNE)
__device__ __forceinline__ u16 bfb(float f){
  union { __bf16 h; u16 u; } x; x.h = (__bf16)f; return x.u;
}
__device__ __forceinline__ u32 pkbf2(float a, float b){
  union { __bf16 h[2]; u32 u; } x; x.h[0] = (__bf16)a; x.h[1] = (__bf16)b; return x.u;
}
__device__ __forceinline__ void unpack8(int4 v, float* o){
  u32 a=(u32)v.x, b=(u32)v.y, c=(u32)v.z, d=(u32)v.w;
  o[0]=__uint_as_float(a<<16); o[1]=__uint_as_float(a&0xffff0000u);
  o[2]=__uint_as_float(b<<16); o[3]=__uint_as_float(b&0xffff0000u);
  o[4]=__uint_as_float(c<<16); o[5]=__uint_as_float(c&0xffff0000u);
  o[6]=__uint_as_float(d<<16); o[7]=__uint_as_float(d&0xffff0000u);
}
// async global->LDS, 16B per lane (dest = uniform base + lane*16)
__device__ __forceinline__ void gload_lds16(const void* gp, void* lp){
  __builtin_amdgcn_global_load_lds(
      (const __attribute__((address_space(1))) unsigned int*)gp,
      (__attribute__((address_space(3))) unsigned int*)lp, 16, 0, 0);
}

// ---------------------------------------------------------------------------
// K0: pack wqb[o][c] = bf16(w_qkv*g_in), wob[c][e] = bf16(w_out)
// ---------------------------------------------------------------------------
__global__ __launch_bounds__(256) void k_pack(const float* __restrict__ wqkv,
                                              const float* __restrict__ gin,
                                              const float* __restrict__ wout,
                                              u16* __restrict__ wqb,
                                              u16* __restrict__ wob)
{
  int i = blockIdx.x*256 + threadIdx.x;
  if (i < OC3*NCH){ int c = i & 255; wqb[i] = bfb(wqkv[i]*gin[c]); }
  else { int j = i - OC3*NCH; wob[j] = bfb(wout[j]); }
}

// ---------------------------------------------------------------------------
// K1: fused rms-norm + transpose + QKV GEMM (bf16 MFMA) + q-softmax.
// Phase 1 now stages x through LDS via global_load_lds (width 16):
//   4 stages x 64 c-rows; wave w stages & packs ONLY its own rows
//   (w*8..w*8+7 per stage) -> no extra barriers, vmcnt-only sync.
//   Per-thread HBM round-trips: 32 scalar loads -> 4 bursts of 8 gloads.
// K-loop / epilogue unchanged from R3 (passed). Native bf16 casts.
// LDS 52.4KB -> 3 blocks/CU.
// ---------------------------------------------------------------------------
__global__ __launch_bounds__(512, 4) void k_qkvx(const float* __restrict__ x,
                                                 const u16* __restrict__ wqb,
                                                 u16* __restrict__ qt,
                                                 u16* __restrict__ kv)
{
  __shared__ __align__(16) char smem[52480];
  float (*Xs)[64]   = (float(*)[64])smem;               // 16384 B (phase-1 only)
  u16*   Bx         = (u16*)(smem + 16384);             // 64*264 u16 = 33792 B
  float (*ssqp)[64] = (float(*)[64])(smem + 50176);     // 2048 B
  float* rl         = (float*)(smem + 52224);           // 256 B
  float (*psx)[64]  = (float(*)[64])smem;               // overlay on dead Xs

  const int t = threadIdx.x, w = t>>6, lane = t&63;
  const int n0 = blockIdx.x*64, b = blockIdx.y;
  const int qw = lane>>4, rr = lane&15;

  // phase 1: stage x via global_load_lds, pack bf16-transposed into Bx,
  // per-n sum-of-squares in fp32
  {
    float ssq = 0.f;
    for (int s=0;s<4;++s){
      asm volatile("s_waitcnt lgkmcnt(0)" ::: "memory");   // Xs reads of prev stage retired
      const float* gp = x + ((size_t)b*NCH + s*64 + w*8 + (lane>>4))*NPIX + n0 + (lane&15)*4;
      gload_lds16(gp,                    &Xs[w*8 + 0][0]);
      gload_lds16(gp + (size_t)4*NPIX,   &Xs[w*8 + 4][0]);
      asm volatile("s_waitcnt vmcnt(0)" ::: "memory");
      u32 pk[4];
      #pragma unroll
      for (int q=0;q<4;q++){
        float v0 = Xs[w*8 + 2*q    ][lane];
        float v1 = Xs[w*8 + 2*q + 1][lane];
        ssq += v0*v0 + v1*v1;
        pk[q] = pkbf2(v0, v1);
      }
      *(int4*)&Bx[lane*264 + s*64 + w*8] = make_int4((int)pk[0],(int)pk[1],(int)pk[2],(int)pk[3]);
    }
    ssqp[w][lane] = ssq;
  }
  __syncthreads();
  if (t < 64){
    float s = 0.f;
    #pragma unroll
    for (int g=0;g<8;g++) s += ssqp[g][t];
    rl[t] = 16.0f / fmaxf(sqrtf(s), 1e-12f);
  }

  f32x4 acc[3][4];
  #pragma unroll
  for (int p=0;p<3;p++)
    #pragma unroll
    for (int nf=0;nf<4;nf++) acc[p][nf] = (f32x4){0.f,0.f,0.f,0.f};

  // barrier-free K-loop: A-frags from global (L2) with 1-iter prefetch
  const u16* aw = wqb + (size_t)(w*16 + rr)*NCH + qw*8;
  bf16x8 caf0 = *(const bf16x8*)(aw);
  bf16x8 caf1 = *(const bf16x8*)(aw + 128*NCH);
  bf16x8 caf2 = *(const bf16x8*)(aw + 256*NCH);
  #pragma unroll
  for (int c0=0; c0<NCH; c0+=32){
    bf16x8 bfr[4];
    #pragma unroll
    for (int nf=0;nf<4;nf++)
      bfr[nf] = *(const bf16x8*)&Bx[(nf*16+rr)*264 + c0 + qw*8];
    bf16x8 naf0 = caf0, naf1 = caf1, naf2 = caf2;
    if (c0 < NCH-32){
      naf0 = *(const bf16x8*)(aw + c0+32);
      naf1 = *(const bf16x8*)(aw + 128*NCH + c0+32);
      naf2 = *(const bf16x8*)(aw + 256*NCH + c0+32);
    }
    #pragma unroll
    for (int nf=0;nf<4;nf++){
      acc[0][nf] = __builtin_amdgcn_mfma_f32_16x16x32_bf16(caf0, bfr[nf], acc[0][nf], 0, 0, 0); // q: D[o][n]
      acc[1][nf] = __builtin_amdgcn_mfma_f32_16x16x32_bf16(bfr[nf], caf1, acc[1][nf], 0, 0, 0); // k: D[n][o]
      acc[2][nf] = __builtin_amdgcn_mfma_f32_16x16x32_bf16(bfr[nf], caf2, acc[2][nf], 0, 0, 0); // v: D[n][o]
    }
    caf0 = naf0; caf1 = naf1; caf2 = naf2;
  }

  __syncthreads();   // (1) rl ready for all waves; Xs dead -> psx usable after next barrier

  // ---- k & v: rl-scale + pack + DIRECT global store (no LDS round-trip)
  // swapped layout: col = rr -> o = w*16+rr ; row = qw*4+reg -> n = nf*16+qw*4+reg
  #pragma unroll
  for (int p=1;p<3;p++){
    u16* base = kv + ((size_t)(b*256 + (p-1)*128 + w*16 + rr))*NPIX + n0;
    #pragma unroll
    for (int nf=0;nf<4;nf++){
      const float4 rv4 = *(const float4*)&rl[nf*16 + qw*4];
      u32 lo = pkbf2(acc[p][nf][0]*rv4.x, acc[p][nf][1]*rv4.y);
      u32 hi = pkbf2(acc[p][nf][2]*rv4.z, acc[p][nf][3]*rv4.w);
      *(int2*)(base + nf*16 + qw*4) = make_int2((int)lo,(int)hi);
    }
  }

  // ---- q: rl-scale + softmax over head_dim (16 in-wave d + 16 partner)
  // normal layout: col = rr -> n = nf*16+rr ; row = qw*4+reg -> o = w*16+qw*4+reg
  float qv[4][4], pm[4], ps[4];
  #pragma unroll
  for (int nf=0;nf<4;nf++){
    float rv = rl[nf*16 + rr];
    float m = -1e30f;
    #pragma unroll
    for (int r=0;r<4;r++){ qv[nf][r] = acc[0][nf][r]*rv; m = fmaxf(m, qv[nf][r]); }
    m = fmaxf(m, __shfl_xor(m, 16, 64));
    m = fmaxf(m, __shfl_xor(m, 32, 64));
    float s = 0.f;
    #pragma unroll
    for (int r=0;r<4;r++){ qv[nf][r] = __expf(qv[nf][r]-m); s += qv[nf][r]; }
    s += __shfl_xor(s, 16, 64);
    s += __shfl_xor(s, 32, 64);
    pm[nf] = m; ps[nf] = s;
  }
  if (lane < 16){
    #pragma unroll
    for (int nf=0;nf<4;nf++){ ssqp[w][nf*16+lane] = pm[nf]; psx[w][nf*16+lane] = ps[nf]; }
  }
  __syncthreads();   // (2) partner partials visible
  {
    const int pw = w^1;   // waves (2h, 2h+1) share head h
    u16* qbase = qt + ((size_t)b*NPIX + n0)*HID + w*16 + qw*4;
    #pragma unroll
    for (int nf=0;nf<4;nf++){
      float om = ssqp[pw][nf*16+rr], os = psx[pw][nf*16+rr];
      float M = fmaxf(pm[nf], om);
      float S = ps[nf]*__expf(pm[nf]-M) + os*__expf(om-M);
      float f = __expf(pm[nf]-M) * SCALE_Q / S;
      u32 lo = pkbf2(qv[nf][0]*f, qv[nf][1]*f);
      u32 hi = pkbf2(qv[nf][2]*f, qv[nf][3]*f);
      *(int2*)(qbase + (size_t)(nf*16+rr)*HID) = make_int2((int)lo,(int)hi);
    }
  }
}

// ---------------------------------------------------------------------------
// K2: k-row reduction: M = max over (4 mem + 4096), inv = 1/sum(exp).
// ---------------------------------------------------------------------------
__global__ __launch_bounds__(256) void k_kred(const u16* __restrict__ kv,
                                              const float* __restrict__ memkv,
                                              float2* __restrict__ kms,
                                              float* __restrict__ ksm)
{
  const int rid = blockIdx.x*4 + (threadIdx.x>>6);
  const int lane = threadIdx.x & 63;
  const int d = rid & 31, h = (rid>>5)&3, b = rid>>7;
  const u16* p = kv + (size_t)(b*256 + h*HDIM + d)*NPIX;
  u32 buf[32];
  #pragma unroll
  for (int j=0;j<8;j++)
    *(int4*)&buf[j*4] = *(const int4*)(p + (size_t)(j*64+lane)*8);
  float m = -1e30f;
  #pragma unroll
  for (int i=0;i<32;i++){
    float lo = __uint_as_float(buf[i]<<16);
    float hi = __uint_as_float(buf[i]&0xffff0000u);
    m = fmaxf(m, fmaxf(lo, hi));
  }
  float mv[4];
  #pragma unroll
  for (int mm=0;mm<4;mm++){ mv[mm] = memkv[(h*HDIM+d)*NMEM + mm]; m = fmaxf(m, mv[mm]); }
  #pragma unroll
  for (int sh=1; sh<64; sh<<=1) m = fmaxf(m, __shfl_xor(m, sh, 64));
  float ssum = 0.f;
  #pragma unroll
  for (int i=0;i<32;i++){
    float lo = __uint_as_float(buf[i]<<16);
    float hi = __uint_as_float(buf[i]&0xffff0000u);
    ssum += __expf(lo-m) + __expf(hi-m);
  }
  #pragma unroll
  for (int sh=1; sh<64; sh<<=1) ssum += __shfl_xor(ssum, sh, 64);
  #pragma unroll
  for (int mm=0;mm<4;mm++) ssum += __expf(mv[mm]-m);
  float inv = 1.0f/ssum;
  if (lane==0) kms[rid] = make_float2(m, inv);
  if (lane<4) ksm[rid*NMEM + lane] = __expf(mv[lane]-m)*inv;
}

// ---------------------------------------------------------------------------
// K3: ctx[b,h,d,e] = sum_tokens exp(k[d,n]-M)*inv * v[e,n]  (32 n-splits)
// ---------------------------------------------------------------------------
__global__ __launch_bounds__(64) void k_ctx(const u16* __restrict__ kv,
                                            const float* __restrict__ memkv,
                                            const float* __restrict__ ksm,
                                            const float2* __restrict__ kms,
                                            float* __restrict__ ctxp)
{
  __shared__ float Ks[32][68];
  __shared__ float Vs[32][68];
  const int bh = blockIdx.x;                // 0..63
  const int s  = blockIdx.y;                // 0..31
  const int b = bh>>2, h = bh&3;
  const int t = threadIdx.x;
  const int d0 = (t>>3)*4, e0 = (t&7)*4;
  float acc[4][4] = {};
  if (s==0){
    #pragma unroll
    for (int m=0;m<4;m++){
      float km[4];
      #pragma unroll
      for (int pi=0;pi<4;pi++) km[pi] = ksm[(bh*HDIM + d0+pi)*NMEM + m];
      #pragma unroll
      for (int q=0;q<4;q++){
        float vm = memkv[((NHEAD+h)*HDIM + e0+q)*NMEM + m];
        #pragma unroll
        for (int pi=0;pi<4;pi++) acc[pi][q] += km[pi]*vm;
      }
    }
  }
  const u16* kb = kv + (size_t)(b*256 +       h*HDIM)*NPIX;
  const u16* vb = kv + (size_t)(b*256 + HID + h*HDIM)*NPIX;
  const int lr = t>>1, lseg = (t&1)*32;
  const float2 ms = kms[bh*HDIM + lr];
  #pragma unroll
  for (int half=0; half<2; ++half){
    const int n0 = s*128 + half*64;
    const u16* kp = kb + (size_t)lr*NPIX + n0 + lseg;
    const u16* vp = vb + (size_t)lr*NPIX + n0 + lseg;
    #pragma unroll
    for (int u=0;u<4;u++){
      int4 kvv = *(const int4*)(kp + u*8);
      int4 vv  = *(const int4*)(vp + u*8);
      float kf[8], vf[8];
      unpack8(kvv,kf); unpack8(vv,vf);
      #pragma unroll
      for (int i=0;i<8;i++) kf[i] = __expf(kf[i]-ms.x)*ms.y;
      *(float4*)&Ks[lr][lseg+u*8]   = make_float4(kf[0],kf[1],kf[2],kf[3]);
      *(float4*)&Ks[lr][lseg+u*8+4] = make_float4(kf[4],kf[5],kf[6],kf[7]);
      *(float4*)&Vs[lr][lseg+u*8]   = make_float4(vf[0],vf[1],vf[2],vf[3]);
      *(float4*)&Vs[lr][lseg+u*8+4] = make_float4(vf[4],vf[5],vf[6],vf[7]);
    }
    __syncthreads();
    #pragma unroll 4
    for (int nn=0;nn<64;nn+=4){
      float kq[4][4] __attribute__((aligned(16)));
      float vq[4][4] __attribute__((aligned(16)));
      #pragma unroll
      for (int pi=0;pi<4;pi++) *(float4*)kq[pi] = *(const float4*)&Ks[d0+pi][nn];
      #pragma unroll
      for (int q=0;q<4;q++)    *(float4*)vq[q]  = *(const float4*)&Vs[e0+q][nn];
      #pragma unroll
      for (int pi=0;pi<4;pi++)
        #pragma unroll
        for (int q=0;q<4;q++)
          acc[pi][q] += kq[pi][0]*vq[q][0] + kq[pi][1]*vq[q][1]
                      + kq[pi][2]*vq[q][2] + kq[pi][3]*vq[q][3];
    }
    __syncthreads();
  }
  #pragma unroll
  for (int pi=0;pi<4;pi++)
    *(float4*)(ctxp + (size_t)(s*64+bh)*1024 + (d0+pi)*32 + e0) =
      make_float4(acc[pi][0],acc[pi][1],acc[pi][2],acc[pi][3]);
}

__global__ __launch_bounds__(256) void k_ctxred(const float* __restrict__ ctxp,
                                                float* __restrict__ ctx)
{
  const int bh = blockIdx.x, t = threadIdx.x;
  float4 s = make_float4(0.f,0.f,0.f,0.f);
  #pragma unroll
  for (int sp=0; sp<32; sp++){
    float4 v = *(const float4*)(ctxp + (size_t)(sp*64+bh)*1024 + t*4);
    s.x+=v.x; s.y+=v.y; s.z+=v.z; s.w+=v.w;
  }
  *(float4*)(ctx + (size_t)bh*1024 + t*4) = s;
}

// ---------------------------------------------------------------------------
// K4 (fused attnout + w_out + rms): per (b, 64-n tile):
//   PV MFMA: ao[e,n] = sum_d ctx[h,d,e]*q[h,d,n]  (ctx->bf16 LDS A,
//   q B-frag loaded DIRECT from qt[b][n][o] — no transpose staging)
//   then out = rms_c( wob . ao + b_out ) * g_out   (A direct from global/L2)
// ---------------------------------------------------------------------------
__global__ __launch_bounds__(256) void k_fout(const u16* __restrict__ qt,
                                              const float* __restrict__ ctx,
                                              const u16* __restrict__ wob,
                                              const float* __restrict__ bout,
                                              const float* __restrict__ gout,
                                              float* __restrict__ out)
{
  __shared__ u16 Cb[4*32*40];     // [h][e][d], stride 40
  __shared__ u16 Ao[64*136];      // [n][e(hid)]
  __shared__ float ssql[4][64];
  const int t = threadIdx.x, w = t>>6, lane = t&63;
  const int n0 = blockIdx.x*64, b = blockIdx.y;
  const int qw = lane>>4, rr = lane&15;

  // stage ctx -> Cb bf16 transposed [h][e][d]
  {
    const float4* c4 = (const float4*)(ctx + (size_t)b*4096);
    const int d = (t>>3)&31, e0 = (t&7)*4;
    #pragma unroll
    for (int h=0;h<4;h++){
      float4 v = c4[t + h*256];
      Cb[(h*32+e0+0)*40 + d] = bfb(v.x);
      Cb[(h*32+e0+1)*40 + d] = bfb(v.y);
      Cb[(h*32+e0+2)*40 + d] = bfb(v.z);
      Cb[(h*32+e0+3)*40 + d] = bfb(v.w);
    }
  }
  __syncthreads();

  // PV MFMA: wave w owns n-frag w (n = w*16 + rr); q direct from qt[b][n][o]
  f32x4 pv[4][2];
  const u16* qp = qt + ((size_t)b*NPIX + n0 + w*16 + rr)*HID;
  #pragma unroll
  for (int h=0;h<4;h++){
    bf16x8 bq = *(const bf16x8*)(qp + h*32 + qw*8);
    #pragma unroll
    for (int ef=0;ef<2;ef++){
      bf16x8 af = *(const bf16x8*)&Cb[(h*32 + ef*16 + rr)*40 + qw*8];
      f32x4 z = (f32x4){0.f,0.f,0.f,0.f};
      pv[h][ef] = __builtin_amdgcn_mfma_f32_16x16x32_bf16(af, bq, z, 0, 0, 0);
    }
  }
  // write ao -> Ao[n][e] (C-layout: col n = w*16+rr, rows e = qw*4+reg)
  #pragma unroll
  for (int h=0;h<4;h++)
    #pragma unroll
    for (int ef=0;ef<2;ef++){
      u32 lohi0 = pkbf2(pv[h][ef][0], pv[h][ef][1]);
      u32 lohi1 = pkbf2(pv[h][ef][2], pv[h][ef][3]);
      *(int2*)&Ao[(w*16+rr)*136 + h*32 + ef*16 + qw*4] = make_int2((int)lohi0,(int)lohi1);
    }
  __syncthreads();

  // w_out GEMM: K=128 over e; A = wob[c][e] direct from global (L2-hot)
  f32x4 acc[4][4];
  #pragma unroll
  for (int i=0;i<4;i++)
    #pragma unroll
    for (int j=0;j<4;j++) acc[i][j] = (f32x4){0.f,0.f,0.f,0.f};
  #pragma unroll
  for (int k0=0; k0<HID; k0+=32){
    bf16x8 af[4], bfr[4];
    #pragma unroll
    for (int mf=0;mf<4;mf++)
      af[mf] = *(const bf16x8*)&wob[(size_t)(w*64 + mf*16 + rr)*HID + k0 + qw*8];
    #pragma unroll
    for (int nf=0;nf<4;nf++)
      bfr[nf] = *(const bf16x8*)&Ao[(nf*16+rr)*136 + k0 + qw*8];
    #pragma unroll
    for (int mf=0;mf<4;mf++)
      #pragma unroll
      for (int nf=0;nf<4;nf++)
        acc[mf][nf] = __builtin_amdgcn_mfma_f32_16x16x32_bf16(af[mf], bfr[nf], acc[mf][nf], 0, 0, 0);
  }
  // bias + column sum-of-squares (full 256 c in this block)
  float pssq[4] = {0.f,0.f,0.f,0.f};
  #pragma unroll
  for (int mf=0;mf<4;mf++)
    #pragma unroll
    for (int reg=0;reg<4;reg++){
      int c = w*64 + mf*16 + qw*4 + reg;
      float bb = bout[c];
      #pragma unroll
      for (int nf=0;nf<4;nf++){
        float v = acc[mf][nf][reg] + bb;
        acc[mf][nf][reg] = v;
        pssq[nf] += v*v;
      }
    }
  #pragma unroll
  for (int nf=0;nf<4;nf++){
    pssq[nf] += __shfl_xor(pssq[nf], 16, 64);
    pssq[nf] += __shfl_xor(pssq[nf], 32, 64);
  }
  if (qw==0){
    #pragma unroll
    for (int nf=0;nf<4;nf++) ssql[w][nf*16+rr] = pssq[nf];
  }
  __syncthreads();
  float rv[4];
  #pragma unroll
  for (int nf=0;nf<4;nf++){
    int col = nf*16 + rr;
    float sm = ssql[0][col]+ssql[1][col]+ssql[2][col]+ssql[3][col];
    rv[nf] = 16.0f / fmaxf(sqrtf(sm), 1e-12f);
  }
  #pragma unroll
  for (int mf=0;mf<4;mf++)
    #pragma unroll
    for (int reg=0;reg<4;reg++){
      int c = w*64 + mf*16 + qw*4 + reg;
      float g = gout[c];
      float* po = out + ((size_t)(b*NCH + c))*NPIX + n0;
      #pragma unroll
      for (int nf=0;nf<4;nf++)
        po[nf*16 + rr] = acc[mf][nf][reg]*rv[nf]*g;
    }
}

// ---------------------------------------------------------------------------
extern "C" void kernel_launch(void* const* d_in, const int* in_sizes, int n_in,
                              void* d_out, int out_size, void* d_ws, size_t ws_size,
                              hipStream_t stream)
{
  const float* x     = (const float*)d_in[0];
  const float* gin   = (const float*)d_in[1];
  const float* memkv = (const float*)d_in[2];
  const float* wqkv  = (const float*)d_in[3];
  const float* wout  = (const float*)d_in[4];
  const float* bout  = (const float*)d_in[5];
  const float* gout  = (const float*)d_in[6];
  float* out = (float*)d_out;

  char* ws = (char*)d_ws;
  u16*    kvb  = (u16*)   (ws);                     // 33,554,432 (k rows 0..127, v rows 128..255 per b)
  u16*    qt   = (u16*)   (ws + 33554432);          // 16,777,216 ([b][n][o] bf16)
  float*  ksm  = (float*) (ws + 50331648);          //     32,768
  float2* kms  = (float2*)(ws + 50364416);          //     16,384
  float*  ctxp = (float*) (ws + 50380800);          //  8,388,608
  float*  ctx  = (float*) (ws + 58769408);          //    262,144
  u16*    wqb  = (u16*)   (ws + 59031552);          //    196,608
  u16*    wob  = (u16*)   (ws + 59228160);          //     65,536  -> total 59,293,696

  hipLaunchKernelGGL(k_pack,   dim3(512),   dim3(256), 0, stream, wqkv, gin, wout, wqb, wob);
  hipLaunchKernelGGL(k_qkvx,   dim3(64,16), dim3(512), 0, stream, x, wqb, qt, kvb);
  hipLaunchKernelGGL(k_kred,   dim3(512),   dim3(256), 0, stream, kvb, memkv, kms, ksm);
  hipLaunchKernelGGL(k_ctx,    dim3(64,32), dim3(64),  0, stream, kvb, memkv, ksm, kms, ctxp);
  hipLaunchKernelGGL(k_ctxred, dim3(64),    dim3(256), 0, stream, ctxp, ctx);
  hipLaunchKernelGGL(k_fout,   dim3(64,16), dim3(256), 0, stream, qt, ctx, wob, bout, gout, out);
}

// Round 6
// 172.484 us; speedup vs baseline: 1.1520x; 1.1520x over previous
//
#include <hip/hip_runtime.h>
#include <math.h>

typedef unsigned short u16;
typedef unsigned int u32;

#define NBATCH 16
#define NCH    256
#define NPIX   4096
#define NHEAD  4
#define HDIM   32
#define NMEM   4
#define HID    128
#define OC3    384
#define SCALE_Q 0.17677669529663687f

typedef __bf16 bf16x8 __attribute__((ext_vector_type(8)));
typedef float  f32x4  __attribute__((ext_vector_type(4)));

// native casts -> compiler emits v_cvt_pk_bf16_f32 (RNE)
__device__ __forceinline__ u16 bfb(float f){
  union { __bf16 h; u16 u; } x; x.h = (__bf16)f; return x.u;
}
__device__ __forceinline__ u32 pkbf2(float a, float b){
  union { __bf16 h[2]; u32 u; } x; x.h[0] = (__bf16)a; x.h[1] = (__bf16)b; return x.u;
}
// async global->LDS, 16B per lane (dest = uniform base + lane*16)
__device__ __forceinline__ void gload_lds16(const void* gp, void* lp){
  __builtin_amdgcn_global_load_lds(
      (const __attribute__((address_space(1))) unsigned int*)gp,
      (__attribute__((address_space(3))) unsigned int*)lp, 16, 0, 0);
}

// ---------------------------------------------------------------------------
// K0: pack wqb[o][c] = bf16(w_qkv*g_in), wob[c][e] = bf16(w_out)
// ---------------------------------------------------------------------------
__global__ __launch_bounds__(256) void k_pack(const float* __restrict__ wqkv,
                                              const float* __restrict__ gin,
                                              const float* __restrict__ wout,
                                              u16* __restrict__ wqb,
                                              u16* __restrict__ wob)
{
  int i = blockIdx.x*256 + threadIdx.x;
  if (i < OC3*NCH){ int c = i & 255; wqb[i] = bfb(wqkv[i]*gin[c]); }
  else { int j = i - OC3*NCH; wob[j] = bfb(wout[j]); }
}

// ---------------------------------------------------------------------------
// K1 (FUSED): rms-norm + QKV GEMM + q-softmax + PER-TILE ctx partial.
// Per (b, 64-n tile):
//   - stage x via global_load_lds, pack bf16 -> Bx[n][c], per-n ssq -> rl
//   - K-loop: q acc normal layout D[o][n]; k,v acc swapped D[n][o]
//   - epilogue:
//       ek = exp(k*rl)  (NO max subtraction: |k|<=~6 -> fp32/bf16 safe)
//       vv = v*rl ; both -> LDS [o][n] (overlay on dead Bx)
//       z[o] = sum_n ek  (in-register + shfl)
//       q softmax over head_dim -> qt[b][n][o]  (unchanged)
//       per-head 16x16x32 MFMAs over n: P[h][d][e] = sum_n ek[d,n]*vv[e,n]
//       write P (4x1024) + z (4x32) partials -> ctxp2[(b,s)][h][1088]
// Replaces the old k_kred / k_ctx / k_ctxred kernels and the 32MB kv buffer.
// ---------------------------------------------------------------------------
__global__ __launch_bounds__(512, 4) void k_qkvx(const float* __restrict__ x,
                                                 const u16* __restrict__ wqb,
                                                 u16* __restrict__ qt,
                                                 float* __restrict__ ctxp2)
{
  __shared__ __align__(16) char smem[52480];
  float (*Xs)[64]   = (float(*)[64])smem;               // 16384 B (phase-1 only)
  u16*   Bx         = (u16*)(smem + 16384);             // 64*264 u16 = 33792 B
  float (*ssqp)[64] = (float(*)[64])(smem + 50176);     // 2048 B
  float* rl         = (float*)(smem + 52224);           // 256 B
  // post-K-loop overlays (Xs and Bx are dead after the K-loop):
  u16*   Ek         = (u16*)smem;                       // 128*72 u16 = 18432 B
  u16*   Vv         = (u16*)(smem + 18432);             // 18432 B (ends 36864)
  float (*psx)[64]  = (float(*)[64])(smem + 36864);     // 2048 B

  const int t = threadIdx.x, w = t>>6, lane = t&63;
  const int n0 = blockIdx.x*64, b = blockIdx.y;
  const int qw = lane>>4, rr = lane&15;

  // phase 1: stage x via global_load_lds, pack bf16-transposed into Bx,
  // per-n sum-of-squares in fp32
  {
    float ssq = 0.f;
    for (int s=0;s<4;++s){
      asm volatile("s_waitcnt lgkmcnt(0)" ::: "memory");   // Xs reads of prev stage retired
      const float* gp = x + ((size_t)b*NCH + s*64 + w*8 + (lane>>4))*NPIX + n0 + (lane&15)*4;
      gload_lds16(gp,                    &Xs[w*8 + 0][0]);
      gload_lds16(gp + (size_t)4*NPIX,   &Xs[w*8 + 4][0]);
      asm volatile("s_waitcnt vmcnt(0)" ::: "memory");
      u32 pk[4];
      #pragma unroll
      for (int q=0;q<4;q++){
        float v0 = Xs[w*8 + 2*q    ][lane];
        float v1 = Xs[w*8 + 2*q + 1][lane];
        ssq += v0*v0 + v1*v1;
        pk[q] = pkbf2(v0, v1);
      }
      *(int4*)&Bx[lane*264 + s*64 + w*8] = make_int4((int)pk[0],(int)pk[1],(int)pk[2],(int)pk[3]);
    }
    ssqp[w][lane] = ssq;
  }
  __syncthreads();                                       // B1
  if (t < 64){
    float s = 0.f;
    #pragma unroll
    for (int g=0;g<8;g++) s += ssqp[g][t];
    rl[t] = 16.0f / fmaxf(sqrtf(s), 1e-12f);
  }

  f32x4 acc[3][4];
  #pragma unroll
  for (int p=0;p<3;p++)
    #pragma unroll
    for (int nf=0;nf<4;nf++) acc[p][nf] = (f32x4){0.f,0.f,0.f,0.f};

  // barrier-free K-loop: A-frags from global (L2) with 1-iter prefetch
  const u16* aw = wqb + (size_t)(w*16 + rr)*NCH + qw*8;
  bf16x8 caf0 = *(const bf16x8*)(aw);
  bf16x8 caf1 = *(const bf16x8*)(aw + 128*NCH);
  bf16x8 caf2 = *(const bf16x8*)(aw + 256*NCH);
  #pragma unroll
  for (int c0=0; c0<NCH; c0+=32){
    bf16x8 bfr[4];
    #pragma unroll
    for (int nf=0;nf<4;nf++)
      bfr[nf] = *(const bf16x8*)&Bx[(nf*16+rr)*264 + c0 + qw*8];
    bf16x8 naf0 = caf0, naf1 = caf1, naf2 = caf2;
    if (c0 < NCH-32){
      naf0 = *(const bf16x8*)(aw + c0+32);
      naf1 = *(const bf16x8*)(aw + 128*NCH + c0+32);
      naf2 = *(const bf16x8*)(aw + 256*NCH + c0+32);
    }
    #pragma unroll
    for (int nf=0;nf<4;nf++){
      acc[0][nf] = __builtin_amdgcn_mfma_f32_16x16x32_bf16(caf0, bfr[nf], acc[0][nf], 0, 0, 0); // q: D[o][n]
      acc[1][nf] = __builtin_amdgcn_mfma_f32_16x16x32_bf16(bfr[nf], caf1, acc[1][nf], 0, 0, 0); // k: D[n][o]
      acc[2][nf] = __builtin_amdgcn_mfma_f32_16x16x32_bf16(bfr[nf], caf2, acc[2][nf], 0, 0, 0); // v: D[n][o]
    }
    caf0 = naf0; caf1 = naf1; caf2 = naf2;
  }

  __syncthreads();   // B2: rl visible; Bx/Xs dead -> Ek/Vv/psx overlays usable

  // ---- ek / vv -> LDS [o][n] (stride 72), z[o] partial
  // swapped layout: o = w*16+rr ; n = nf*16+qw*4+reg
  float zk = 0.f;
  #pragma unroll
  for (int nf=0;nf<4;nf++){
    const float4 rv4 = *(const float4*)&rl[nf*16 + qw*4];
    float e0 = __expf(acc[1][nf][0]*rv4.x);
    float e1 = __expf(acc[1][nf][1]*rv4.y);
    float e2 = __expf(acc[1][nf][2]*rv4.z);
    float e3 = __expf(acc[1][nf][3]*rv4.w);
    zk += e0+e1+e2+e3;
    *(int2*)&Ek[(w*16+rr)*72 + nf*16 + qw*4] =
        make_int2((int)pkbf2(e0,e1), (int)pkbf2(e2,e3));
    float v0 = acc[2][nf][0]*rv4.x, v1 = acc[2][nf][1]*rv4.y;
    float v2 = acc[2][nf][2]*rv4.z, v3 = acc[2][nf][3]*rv4.w;
    *(int2*)&Vv[(w*16+rr)*72 + nf*16 + qw*4] =
        make_int2((int)pkbf2(v0,v1), (int)pkbf2(v2,v3));
  }
  zk += __shfl_xor(zk, 16, 64);
  zk += __shfl_xor(zk, 32, 64);

  // ---- q: rl-scale + softmax over head_dim (16 in-wave d + 16 partner)
  // normal layout: col = rr -> n = nf*16+rr ; row = qw*4+reg -> o = w*16+qw*4+reg
  float qv[4][4], pm[4], ps[4];
  #pragma unroll
  for (int nf=0;nf<4;nf++){
    float rv = rl[nf*16 + rr];
    float m = -1e30f;
    #pragma unroll
    for (int r=0;r<4;r++){ qv[nf][r] = acc[0][nf][r]*rv; m = fmaxf(m, qv[nf][r]); }
    m = fmaxf(m, __shfl_xor(m, 16, 64));
    m = fmaxf(m, __shfl_xor(m, 32, 64));
    float s = 0.f;
    #pragma unroll
    for (int r=0;r<4;r++){ qv[nf][r] = __expf(qv[nf][r]-m); s += qv[nf][r]; }
    s += __shfl_xor(s, 16, 64);
    s += __shfl_xor(s, 32, 64);
    pm[nf] = m; ps[nf] = s;
  }
  if (lane < 16){
    #pragma unroll
    for (int nf=0;nf<4;nf++){ ssqp[w][nf*16+lane] = pm[nf]; psx[w][nf*16+lane] = ps[nf]; }
  }
  __syncthreads();   // B3: partner partials + Ek/Vv visible
  {
    const int pw = w^1;   // waves (2h, 2h+1) share head h
    u16* qbase = qt + ((size_t)b*NPIX + n0)*HID + w*16 + qw*4;
    #pragma unroll
    for (int nf=0;nf<4;nf++){
      float om = ssqp[pw][nf*16+rr], os = psx[pw][nf*16+rr];
      float M = fmaxf(pm[nf], om);
      float S = ps[nf]*__expf(pm[nf]-M) + os*__expf(om-M);
      float f = __expf(pm[nf]-M) * SCALE_Q / S;
      u32 lo = pkbf2(qv[nf][0]*f, qv[nf][1]*f);
      u32 hi = pkbf2(qv[nf][2]*f, qv[nf][3]*f);
      *(int2*)(qbase + (size_t)(nf*16+rr)*HID) = make_int2((int)lo,(int)hi);
    }
  }

  // ---- ctx partial GEMM: wave w -> head h=w>>1, e-half eh=w&1
  // P[d][e] = sum_{n<64} ek[d,n]*vv[e,n]  via 16x16x32 MFMA (K = n)
  {
    const int h = w>>1, eh = w&1;
    f32x4 pacc[2] = {(f32x4){0.f,0.f,0.f,0.f},(f32x4){0.f,0.f,0.f,0.f}};
    #pragma unroll
    for (int ks=0; ks<2; ks++){
      bf16x8 bv = *(const bf16x8*)&Vv[(h*32+eh*16+rr)*72 + ks*32 + qw*8];
      #pragma unroll
      for (int i=0;i<2;i++){
        bf16x8 ae = *(const bf16x8*)&Ek[(h*32+i*16+rr)*72 + ks*32 + qw*8];
        pacc[i] = __builtin_amdgcn_mfma_f32_16x16x32_bf16(ae, bv, pacc[i], 0, 0, 0);
      }
    }
    // D layout: row (qw*4+reg) -> d-in-frag, col rr -> e-in-frag
    float* pb = ctxp2 + ((size_t)((b*64 + blockIdx.x)*4 + h))*1088;
    #pragma unroll
    for (int i=0;i<2;i++)
      #pragma unroll
      for (int reg=0;reg<4;reg++)
        pb[(i*16+qw*4+reg)*32 + eh*16 + rr] = pacc[i][reg];
    // z: o = w*16+rr -> h = w>>1 (same), d = (w&1)*16+rr
    if (qw==0) pb[1024 + (w&1)*16 + rr] = zk;
  }
}

// ---------------------------------------------------------------------------
// K2 (new): reduce per-tile partials + memory tokens -> ctx[b][h][d][e]
// ctx = (sum_s P_s + sum_m ek_mem*v_mem) / (sum_s z_s + sum_m ek_mem)
// ---------------------------------------------------------------------------
__global__ __launch_bounds__(256) void k_fin(const float* __restrict__ ctxp2,
                                             const float* __restrict__ memkv,
                                             float* __restrict__ ctx)
{
  const int bh = blockIdx.x, b = bh>>2, h = bh&3, t = threadIdx.x;
  const int d = t>>3, e0 = (t&7)*4;
  float4 ps = make_float4(0.f,0.f,0.f,0.f);
  float z = 0.f;
  for (int s=0;s<64;s++){
    const float* pb = ctxp2 + ((size_t)((b*64+s)*4+h))*1088;
    float4 v = *(const float4*)(pb + d*32 + e0);
    ps.x+=v.x; ps.y+=v.y; ps.z+=v.z; ps.w+=v.w;
    z += pb[1024 + d];
  }
  #pragma unroll
  for (int m=0;m<4;m++){
    float em = __expf(memkv[(h*HDIM+d)*NMEM + m]);
    z += em;
    ps.x += em*memkv[512 + (h*HDIM+e0+0)*NMEM + m];
    ps.y += em*memkv[512 + (h*HDIM+e0+1)*NMEM + m];
    ps.z += em*memkv[512 + (h*HDIM+e0+2)*NMEM + m];
    ps.w += em*memkv[512 + (h*HDIM+e0+3)*NMEM + m];
  }
  float inv = 1.0f/z;
  *(float4*)(ctx + (size_t)bh*1024 + d*32 + e0) =
      make_float4(ps.x*inv, ps.y*inv, ps.z*inv, ps.w*inv);
}

// ---------------------------------------------------------------------------
// K4 (fused attnout + w_out + rms): per (b, 64-n tile):
//   PV MFMA: ao[e,n] = sum_d ctx[h,d,e]*q[h,d,n]  (ctx->bf16 LDS A,
//   q B-frag loaded DIRECT from qt[b][n][o] — no transpose staging)
//   then out = rms_c( wob . ao + b_out ) * g_out   (A direct from global/L2)
// ---------------------------------------------------------------------------
__global__ __launch_bounds__(256) void k_fout(const u16* __restrict__ qt,
                                              const float* __restrict__ ctx,
                                              const u16* __restrict__ wob,
                                              const float* __restrict__ bout,
                                              const float* __restrict__ gout,
                                              float* __restrict__ out)
{
  __shared__ u16 Cb[4*32*40];     // [h][e][d], stride 40
  __shared__ u16 Ao[64*136];      // [n][e(hid)]
  __shared__ float ssql[4][64];
  const int t = threadIdx.x, w = t>>6, lane = t&63;
  const int n0 = blockIdx.x*64, b = blockIdx.y;
  const int qw = lane>>4, rr = lane&15;

  // stage ctx -> Cb bf16 transposed [h][e][d]
  {
    const float4* c4 = (const float4*)(ctx + (size_t)b*4096);
    const int d = (t>>3)&31, e0 = (t&7)*4;
    #pragma unroll
    for (int h=0;h<4;h++){
      float4 v = c4[t + h*256];
      Cb[(h*32+e0+0)*40 + d] = bfb(v.x);
      Cb[(h*32+e0+1)*40 + d] = bfb(v.y);
      Cb[(h*32+e0+2)*40 + d] = bfb(v.z);
      Cb[(h*32+e0+3)*40 + d] = bfb(v.w);
    }
  }
  __syncthreads();

  // PV MFMA: wave w owns n-frag w (n = w*16 + rr); q direct from qt[b][n][o]
  f32x4 pv[4][2];
  const u16* qp = qt + ((size_t)b*NPIX + n0 + w*16 + rr)*HID;
  #pragma unroll
  for (int h=0;h<4;h++){
    bf16x8 bq = *(const bf16x8*)(qp + h*32 + qw*8);
    #pragma unroll
    for (int ef=0;ef<2;ef++){
      bf16x8 af = *(const bf16x8*)&Cb[(h*32 + ef*16 + rr)*40 + qw*8];
      f32x4 z = (f32x4){0.f,0.f,0.f,0.f};
      pv[h][ef] = __builtin_amdgcn_mfma_f32_16x16x32_bf16(af, bq, z, 0, 0, 0);
    }
  }
  // write ao -> Ao[n][e] (C-layout: col n = w*16+rr, rows e = qw*4+reg)
  #pragma unroll
  for (int h=0;h<4;h++)
    #pragma unroll
    for (int ef=0;ef<2;ef++){
      u32 lohi0 = pkbf2(pv[h][ef][0], pv[h][ef][1]);
      u32 lohi1 = pkbf2(pv[h][ef][2], pv[h][ef][3]);
      *(int2*)&Ao[(w*16+rr)*136 + h*32 + ef*16 + qw*4] = make_int2((int)lohi0,(int)lohi1);
    }
  __syncthreads();

  // w_out GEMM: K=128 over e; A = wob[c][e] direct from global (L2-hot)
  f32x4 acc[4][4];
  #pragma unroll
  for (int i=0;i<4;i++)
    #pragma unroll
    for (int j=0;j<4;j++) acc[i][j] = (f32x4){0.f,0.f,0.f,0.f};
  #pragma unroll
  for (int k0=0; k0<HID; k0+=32){
    bf16x8 af[4], bfr[4];
    #pragma unroll
    for (int mf=0;mf<4;mf++)
      af[mf] = *(const bf16x8*)&wob[(size_t)(w*64 + mf*16 + rr)*HID + k0 + qw*8];
    #pragma unroll
    for (int nf=0;nf<4;nf++)
      bfr[nf] = *(const bf16x8*)&Ao[(nf*16+rr)*136 + k0 + qw*8];
    #pragma unroll
    for (int mf=0;mf<4;mf++)
      #pragma unroll
      for (int nf=0;nf<4;nf++)
        acc[mf][nf] = __builtin_amdgcn_mfma_f32_16x16x32_bf16(af[mf], bfr[nf], acc[mf][nf], 0, 0, 0);
  }
  // bias + column sum-of-squares (full 256 c in this block)
  float pssq[4] = {0.f,0.f,0.f,0.f};
  #pragma unroll
  for (int mf=0;mf<4;mf++)
    #pragma unroll
    for (int reg=0;reg<4;reg++){
      int c = w*64 + mf*16 + qw*4 + reg;
      float bb = bout[c];
      #pragma unroll
      for (int nf=0;nf<4;nf++){
        float v = acc[mf][nf][reg] + bb;
        acc[mf][nf][reg] = v;
        pssq[nf] += v*v;
      }
    }
  #pragma unroll
  for (int nf=0;nf<4;nf++){
    pssq[nf] += __shfl_xor(pssq[nf], 16, 64);
    pssq[nf] += __shfl_xor(pssq[nf], 32, 64);
  }
  if (qw==0){
    #pragma unroll
    for (int nf=0;nf<4;nf++) ssql[w][nf*16+rr] = pssq[nf];
  }
  __syncthreads();
  float rv[4];
  #pragma unroll
  for (int nf=0;nf<4;nf++){
    int col = nf*16 + rr;
    float sm = ssql[0][col]+ssql[1][col]+ssql[2][col]+ssql[3][col];
    rv[nf] = 16.0f / fmaxf(sqrtf(sm), 1e-12f);
  }
  #pragma unroll
  for (int mf=0;mf<4;mf++)
    #pragma unroll
    for (int reg=0;reg<4;reg++){
      int c = w*64 + mf*16 + qw*4 + reg;
      float g = gout[c];
      float* po = out + ((size_t)(b*NCH + c))*NPIX + n0;
      #pragma unroll
      for (int nf=0;nf<4;nf++)
        po[nf*16 + rr] = acc[mf][nf][reg]*rv[nf]*g;
    }
}

// ---------------------------------------------------------------------------
extern "C" void kernel_launch(void* const* d_in, const int* in_sizes, int n_in,
                              void* d_out, int out_size, void* d_ws, size_t ws_size,
                              hipStream_t stream)
{
  const float* x     = (const float*)d_in[0];
  const float* gin   = (const float*)d_in[1];
  const float* memkv = (const float*)d_in[2];
  const float* wqkv  = (const float*)d_in[3];
  const float* wout  = (const float*)d_in[4];
  const float* bout  = (const float*)d_in[5];
  const float* gout  = (const float*)d_in[6];
  float* out = (float*)d_out;

  char* ws = (char*)d_ws;
  u16*    qt    = (u16*)   (ws);                    // 16,777,216 ([b][n][o] bf16)
  float*  ctxp2 = (float*) (ws + 16777216);         // 17,825,792 (16*64*4*1088*4)
  float*  ctx   = (float*) (ws + 34603008);         //    262,144
  u16*    wqb   = (u16*)   (ws + 34865152);         //    196,608
  u16*    wob   = (u16*)   (ws + 35061760);         //     65,536 -> total 35,127,296
  hipLaunchKernelGGL(k_pack, dim3(512),   dim3(256), 0, stream, wqkv, gin, wout, wqb, wob);
  hipLaunchKernelGGL(k_qkvx, dim3(64,16), dim3(512), 0, stream, x, wqb, qt, ctxp2);
  hipLaunchKernelGGL(k_fin,  dim3(64),    dim3(256), 0, stream, ctxp2, memkv, ctx);
  hipLaunchKernelGGL(k_fout, dim3(64,16), dim3(256), 0, stream, qt, ctx, wob, bout, gout, out);
}